// Round 10
// baseline (407.305 us; speedup 1.0000x reference)
//
#include <hip/hip_runtime.h>
#include <math.h>

#define N_COLS 4096
#define N_BATCH 256
#define N_ITER 200
#define THREADS 1024
#define CPT 4              // 1024 * 4 = 4096 columns
#define NWAVES (THREADS / 64)

typedef float f32x2 __attribute__((ext_vector_type(2)));

__device__ __forceinline__ float readlane_f(float x, int lane) {
    return __int_as_float(__builtin_amdgcn_readlane(__float_as_int(x), lane));
}

// ---------------------------------------------------------------------------
// Kernel 1: global Cmax = max(s^2, (s-15)^2) over all elements (parabola max
// over anchors is at an endpoint) — bitwise identical to reference C values.
// ---------------------------------------------------------------------------
__global__ void cmax_kernel(const float* __restrict__ scores,
                            unsigned int* __restrict__ ws) {
    int idx = blockIdx.x * blockDim.x + threadIdx.x;
    float m = 0.0f;
    for (int i = idx; i < N_BATCH * N_COLS; i += gridDim.x * blockDim.x) {
        float s = scores[i];
        float t = s - 15.0f;
        m = fmaxf(m, fmaxf(s * s, t * t));
    }
    #pragma unroll
    for (int off = 32; off > 0; off >>= 1)
        m = fmaxf(m, __shfl_xor(m, off));
    __shared__ float sm[4];
    if ((threadIdx.x & 63) == 0) sm[threadIdx.x >> 6] = m;
    __syncthreads();
    if (threadIdx.x == 0) {
        float mm = fmaxf(fmaxf(sm[0], sm[1]), fmaxf(sm[2], sm[3]));
        atomicMax(ws, __float_as_uint(mm));  // all >= 0: uint order == float order
    }
}

// ---------------------------------------------------------------------------
// Kernel 2: 200 Sinkhorn iterations, scaling form, packed-f32 arithmetic.
//   wps[c][k] = (w^(k+1), w^(k+1))  splatted, iteration-invariant
//   up[k]     = (u[15-k], u[7-k])   packed Estrin pairs
//   S = Sv.x + Sv.y*w^8 via v_pk_fma_f32 ; vn = rcp(S)
//   Tpp[k] = (Tp[15-k], Tp[7-k]) via v_pk_fma_f32
// Boundary (this round's change): select-exchange shfl reduce (proven) ->
// tstage write -> barrier -> 4 strided LDS reads + 2 shfl_xor merge ->
// rcp -> u broadcast via v_readlane (constant lane indices, no LDS round-trip).
// ---------------------------------------------------------------------------
__global__ __launch_bounds__(THREADS, 1) void sinkhorn_kernel(
    const float* __restrict__ scores,
    const unsigned int* __restrict__ ws,
    float* __restrict__ out)
{
    const int b = blockIdx.x;
    const int t = threadIdx.x;
    const int lane = t & 63;
    const int wv = t >> 6;

    __shared__ __align__(16) float tstage[2][NWAVES][16];

    const float invC = 1.0f / __uint_as_float(ws[0]);

    // iteration-invariant splatted powers (w^1..w^8) per column
    f32x2 wps[CPT][8];
    float v[CPT];
    const float* srow = scores + b * N_COLS;
    #pragma unroll
    for (int c = 0; c < CPT; ++c) {
        float s = srow[t + THREADS * c];
        float w = expf(20.0f * invC * s);
        float p = w;
        wps[c][0].x = p; wps[c][0].y = p;
        #pragma unroll
        for (int k = 1; k < 8; ++k) {
            p *= w;
            wps[c][k].x = p; wps[c][k].y = p;
        }
    }

    // initial u (g0 = 0) in packed layout: up[k] = (u[15-k], u[7-k])
    f32x2 up[8];
    #pragma unroll
    for (int k = 0; k < 8; ++k) {
        up[k].x = expf(-10.0f * invC * (float)(k * k));
        up[k].y = expf(-10.0f * invC * (float)((8 + k) * (8 + k)));
    }

    const int jown = (lane >> 2) & 15;                    // HW-verified mapping
    const float nuown = (jown == 15) ? 4081.0f : 1.0f;
    const int q = lane & 3;

    int buf = 0;
    for (int it = 0; it < N_ITER; ++it) {
        f32x2 Tpp[8];
        #pragma unroll
        for (int c = 0; c < CPT; ++c) {
            // Sv = (Slo, Shi), Estrin split at w^8 — packed FMA
            f32x2 Sv = up[0];
            #pragma unroll
            for (int k = 1; k < 8; ++k)
                Sv = __builtin_elementwise_fma(up[k], wps[c][k - 1], Sv);
            const float S = fmaf(Sv.y, wps[c][7].x, Sv.x);
            const float vn = __builtin_amdgcn_rcpf(S);
            v[c] = vn;
            f32x2 m;
            m.x = vn;
            m.y = vn * wps[c][7].x;   // q = vn * w^8
            if (c == 0) {
                Tpp[0] = m;
                #pragma unroll
                for (int k = 1; k < 8; ++k) Tpp[k] = m * wps[c][k - 1];
            } else {
                Tpp[0] += m;
                #pragma unroll
                for (int k = 1; k < 8; ++k)
                    Tpp[k] = __builtin_elementwise_fma(m, wps[c][k - 1], Tpp[k]);
            }
        }

        // --- proven intra-wave select-exchange reduce: 17 shfl ---
        // Tp[m] (j=m) = Tpp[7-m].y ; Tp[m+8] = Tpp[7-m].x
        float r8[8];
        {
            const bool hi = (lane & 32) != 0;
            #pragma unroll
            for (int m8 = 0; m8 < 8; ++m8) {
                f32x2 pr = Tpp[7 - m8];
                float keep = hi ? pr.x : pr.y;
                float give = hi ? pr.y : pr.x;
                r8[m8] = keep + __shfl_xor(give, 32);
            }
        }
        float r4[4];
        {
            const bool hi = (lane & 16) != 0;
            #pragma unroll
            for (int m4 = 0; m4 < 4; ++m4) {
                float keep = hi ? r8[m4 + 4] : r8[m4];
                float give = hi ? r8[m4] : r8[m4 + 4];
                r4[m4] = keep + __shfl_xor(give, 16);
            }
        }
        float r2[2];
        {
            const bool hi = (lane & 8) != 0;
            #pragma unroll
            for (int m2 = 0; m2 < 2; ++m2) {
                float keep = hi ? r4[m2 + 2] : r4[m2];
                float give = hi ? r4[m2] : r4[m2 + 2];
                r2[m2] = keep + __shfl_xor(give, 8);
            }
        }
        float x;
        {
            const bool hi = (lane & 4) != 0;
            float keep = hi ? r2[1] : r2[0];
            float give = hi ? r2[0] : r2[1];
            x = keep + __shfl_xor(give, 4);
        }
        x += __shfl_xor(x, 2);
        x += __shfl_xor(x, 1);
        // x = wave-total of Tp[jown]

        if (q == 0) tstage[buf][wv][jown] = x;
        __syncthreads();

        // crosswave: 4 strided reads (2-way bank aliasing = free) + 2 shfl merge
        float T = 0.0f;
        #pragma unroll
        for (int i = 0; i < 4; ++i)
            T += tstage[buf][q + 4 * i][jown];
        T += __shfl_xor(T, 1);
        T += __shfl_xor(T, 2);

        const float uown = nuown * __builtin_amdgcn_rcpf(T);

        // u broadcast via readlane (lanes 4j..4j+3 hold u_j; use lane 4j)
        #pragma unroll
        for (int k = 0; k < 8; ++k) {
            up[k].x = readlane_f(uown, 4 * (15 - k));
            up[k].y = readlane_f(uown, 4 * (7 - k));
        }
        buf ^= 1;
    }

    // epilogue: A[b,n,j] = vn * u_j * w^(15-j), j = 0..14
    // u[j]: j<=7 -> up[7-j].y ; j>=8 -> up[15-j].x
    float uf[15];
    #pragma unroll
    for (int j = 0; j < 8; ++j) uf[j] = up[7 - j].y;
    #pragma unroll
    for (int j = 8; j < 15; ++j) uf[j] = up[15 - j].x;

    #pragma unroll
    for (int c = 0; c < CPT; ++c) {
        const int n = t + THREADS * c;
        float* o = out + ((size_t)b * N_COLS + n) * 15;
        const float vn = v[c];
        const float qq = vn * wps[c][7].x;           // vn * w^8
        #pragma unroll
        for (int j = 0; j < 7; ++j) o[j] = qq * wps[c][6 - j].x * uf[j];   // w^15..w^9
        o[7] = qq * uf[7];                                                 // w^8
        #pragma unroll
        for (int j = 8; j < 15; ++j) o[j] = vn * wps[c][14 - j].x * uf[j]; // w^7..w^1
    }
}

extern "C" void kernel_launch(void* const* d_in, const int* in_sizes, int n_in,
                              void* d_out, int out_size, void* d_ws, size_t ws_size,
                              hipStream_t stream) {
    const float* scores = (const float*)d_in[0];
    unsigned int* ws = (unsigned int*)d_ws;
    float* out = (float*)d_out;

    hipMemsetAsync(d_ws, 0, sizeof(unsigned int), stream);
    cmax_kernel<<<256, 256, 0, stream>>>(scores, ws);
    sinkhorn_kernel<<<N_BATCH, THREADS, 0, stream>>>(scores, ws, out);
}

// Round 12
// 366.620 us; speedup vs baseline: 1.1110x; 1.1110x over previous
//
#include <hip/hip_runtime.h>
#include <math.h>

#define N_COLS 4096
#define N_BATCH 256
#define N_ITER 200
#define THREADS 1024
#define CPT 4              // 1024 * 4 = 4096 columns
#define NWAVES (THREADS / 64)

typedef float f32x2 __attribute__((ext_vector_type(2)));

// ---------------------------------------------------------------------------
// Kernel 1: global Cmax = max(s^2, (s-15)^2) over all elements (parabola max
// over anchors is at an endpoint) — bitwise identical to reference C values.
// ---------------------------------------------------------------------------
__global__ void cmax_kernel(const float* __restrict__ scores,
                            unsigned int* __restrict__ ws) {
    int idx = blockIdx.x * blockDim.x + threadIdx.x;
    float m = 0.0f;
    for (int i = idx; i < N_BATCH * N_COLS; i += gridDim.x * blockDim.x) {
        float s = scores[i];
        float t = s - 15.0f;
        m = fmaxf(m, fmaxf(s * s, t * t));
    }
    #pragma unroll
    for (int off = 32; off > 0; off >>= 1)
        m = fmaxf(m, __shfl_xor(m, off));
    __shared__ float sm[4];
    if ((threadIdx.x & 63) == 0) sm[threadIdx.x >> 6] = m;
    __syncthreads();
    if (threadIdx.x == 0) {
        float mm = fmaxf(fmaxf(sm[0], sm[1]), fmaxf(sm[2], sm[3]));
        atomicMax(ws, __float_as_uint(mm));  // all >= 0: uint order == float order
    }
}

// ---------------------------------------------------------------------------
// Kernel 2: 200 Sinkhorn iterations, scaling form, packed-f32 arithmetic.
//   wps[c][k] = (w^(k+1), w^(k+1))  splatted, iteration-invariant
//   up[k]     = (u[15-k], u[7-k])   packed Estrin pairs (LDS kept in this
//                                    layout so float4 read-back needs no movs)
//   S = Sv.x + Sv.y*w^8 via v_pk_fma_f32 ; vn = rcp(S)
//   Tpp[k] = (Tp[15-k], Tp[7-k]) via v_pk_fma_f32
// Round-11 change (one variable): tstage transposed to [j][wv] (rows padded
// to 20 floats), so the crosswave fan-in is ONE ds_read_b128 (4-wave slice)
// + 2 proven shfl_xor merges across the 4-lane group, instead of 16 b32
// reads. Write side 2-way bank-aliased (free per m136). Everything else is
// bit-identical to the proven round-8 structure (347 us).
// ---------------------------------------------------------------------------
__global__ __launch_bounds__(THREADS, 1) void sinkhorn_kernel(
    const float* __restrict__ scores,
    const unsigned int* __restrict__ ws,
    float* __restrict__ out)
{
    const int b = blockIdx.x;
    const int t = threadIdx.x;
    const int lane = t & 63;
    const int wv = t >> 6;

    __shared__ __align__(16) f32x2 u_sh2[8];
    __shared__ __align__(16) float tstage[2][16][20];  // [buf][j][wv], pad 20

    const float invC = 1.0f / __uint_as_float(ws[0]);

    // iteration-invariant splatted powers (w^1..w^8) per column
    f32x2 wps[CPT][8];
    float v[CPT];
    const float* srow = scores + b * N_COLS;
    #pragma unroll
    for (int c = 0; c < CPT; ++c) {
        float s = srow[t + THREADS * c];
        float w = expf(20.0f * invC * s);
        float p = w;
        wps[c][0].x = p; wps[c][0].y = p;
        #pragma unroll
        for (int k = 1; k < 8; ++k) {
            p *= w;
            wps[c][k].x = p; wps[c][k].y = p;
        }
    }

    // initial u (g0 = 0) in packed layout: up[k] = (u[15-k], u[7-k])
    f32x2 up[8];
    #pragma unroll
    for (int k = 0; k < 8; ++k) {
        up[k].x = expf(-10.0f * invC * (float)(k * k));
        up[k].y = expf(-10.0f * invC * (float)((8 + k) * (8 + k)));
    }

    const int jown = (lane >> 2) & 15;                    // HW-verified mapping
    const float nuown = (jown == 15) ? 4081.0f : 1.0f;
    const int q = lane & 3;
    // packed-layout float index for u_sh2 writer (round-8 proven)
    const int uidx = (jown >= 8) ? (30 - 2 * jown) : (15 - 2 * jown);

    int buf = 0;
    for (int it = 0; it < N_ITER; ++it) {
        f32x2 Tpp[8];
        #pragma unroll
        for (int c = 0; c < CPT; ++c) {
            // Sv = (Slo, Shi), Estrin split at w^8 — packed FMA
            f32x2 Sv = up[0];
            #pragma unroll
            for (int k = 1; k < 8; ++k)
                Sv = __builtin_elementwise_fma(up[k], wps[c][k - 1], Sv);
            const float S = fmaf(Sv.y, wps[c][7].x, Sv.x);
            const float vn = __builtin_amdgcn_rcpf(S);
            v[c] = vn;
            f32x2 m;
            m.x = vn;
            m.y = vn * wps[c][7].x;   // q = vn * w^8
            if (c == 0) {
                Tpp[0] = m;
                #pragma unroll
                for (int k = 1; k < 8; ++k) Tpp[k] = m * wps[c][k - 1];
            } else {
                Tpp[0] += m;
                #pragma unroll
                for (int k = 1; k < 8; ++k)
                    Tpp[k] = __builtin_elementwise_fma(m, wps[c][k - 1], Tpp[k]);
            }
        }

        // --- proven intra-wave select-exchange reduce: 17 shfl ---
        // Tp[m] (j=m) = Tpp[7-m].y ; Tp[m+8] = Tpp[7-m].x
        float r8[8];
        {
            const bool hi = (lane & 32) != 0;
            #pragma unroll
            for (int m8 = 0; m8 < 8; ++m8) {
                f32x2 pr = Tpp[7 - m8];
                float keep = hi ? pr.x : pr.y;
                float give = hi ? pr.y : pr.x;
                r8[m8] = keep + __shfl_xor(give, 32);
            }
        }
        float r4[4];
        {
            const bool hi = (lane & 16) != 0;
            #pragma unroll
            for (int m4 = 0; m4 < 4; ++m4) {
                float keep = hi ? r8[m4 + 4] : r8[m4];
                float give = hi ? r8[m4] : r8[m4 + 4];
                r4[m4] = keep + __shfl_xor(give, 16);
            }
        }
        float r2[2];
        {
            const bool hi = (lane & 8) != 0;
            #pragma unroll
            for (int m2 = 0; m2 < 2; ++m2) {
                float keep = hi ? r4[m2 + 2] : r4[m2];
                float give = hi ? r4[m2] : r4[m2 + 2];
                r2[m2] = keep + __shfl_xor(give, 8);
            }
        }
        float x;
        {
            const bool hi = (lane & 4) != 0;
            float keep = hi ? r2[1] : r2[0];
            float give = hi ? r2[0] : r2[1];
            x = keep + __shfl_xor(give, 4);
        }
        x += __shfl_xor(x, 2);
        x += __shfl_xor(x, 1);
        // x = wave-total of Tp[jown]

        if (q == 0) tstage[buf][jown][wv] = x;   // 2-way bank aliasing: free
        __syncthreads();

        // crosswave: ONE b128 read of 4-wave slice + 2 shfl merges over q-group
        float4 xx = *(const float4*)&tstage[buf][jown][4 * q];
        float T = (xx.x + xx.y) + (xx.z + xx.w);
        T += __shfl_xor(T, 1);
        T += __shfl_xor(T, 2);

        const float uown = nuown * __builtin_amdgcn_rcpf(T);
        if (q == 0) ((float*)u_sh2)[uidx] = uown;  // packed-layout store

        // read back our own wave's writes; float4 loads deliver up[] pairs
        {
            const float4* u4 = (const float4*)u_sh2;
            #pragma unroll
            for (int q4 = 0; q4 < 4; ++q4) {
                float4 uu = u4[q4];
                up[2 * q4 + 0].x = uu.x; up[2 * q4 + 0].y = uu.y;
                up[2 * q4 + 1].x = uu.z; up[2 * q4 + 1].y = uu.w;
            }
        }
        buf ^= 1;
    }

    // epilogue: A[b,n,j] = vn * u_j * w^(15-j), j = 0..14
    // u[j]: j<=7 -> up[7-j].y ; j>=8 -> up[15-j].x
    float uf[15];
    #pragma unroll
    for (int j = 0; j < 8; ++j) uf[j] = up[7 - j].y;
    #pragma unroll
    for (int j = 8; j < 15; ++j) uf[j] = up[15 - j].x;

    #pragma unroll
    for (int c = 0; c < CPT; ++c) {
        const int n = t + THREADS * c;
        float* o = out + ((size_t)b * N_COLS + n) * 15;
        const float vn = v[c];
        const float qq = vn * wps[c][7].x;           // vn * w^8
        #pragma unroll
        for (int j = 0; j < 7; ++j) o[j] = qq * wps[c][6 - j].x * uf[j];   // w^15..w^9
        o[7] = qq * uf[7];                                                 // w^8
        #pragma unroll
        for (int j = 8; j < 15; ++j) o[j] = vn * wps[c][14 - j].x * uf[j]; // w^7..w^1
    }
}

extern "C" void kernel_launch(void* const* d_in, const int* in_sizes, int n_in,
                              void* d_out, int out_size, void* d_ws, size_t ws_size,
                              hipStream_t stream) {
    const float* scores = (const float*)d_in[0];
    unsigned int* ws = (unsigned int*)d_ws;
    float* out = (float*)d_out;

    hipMemsetAsync(d_ws, 0, sizeof(unsigned int), stream);
    cmax_kernel<<<256, 256, 0, stream>>>(scores, ws);
    sinkhorn_kernel<<<N_BATCH, THREADS, 0, stream>>>(scores, ws, out);
}